// Round 8
// baseline (295.023 us; speedup 1.0000x reference)
//
#include <hip/hip_runtime.h>
#include <stdint.h>

#define SEQ   2048
#define NDIM  1024
#define NH    16
#define HD    64
#define KDIM  1024

typedef short  short8  __attribute__((ext_vector_type(8)));
typedef float  floatx4 __attribute__((ext_vector_type(4)));
typedef unsigned short ushort4v __attribute__((ext_vector_type(4)));
typedef _Float16 half8 __attribute__((ext_vector_type(8)));
typedef __fp16  fp16x2 __attribute__((ext_vector_type(2)));
typedef unsigned int uint4v __attribute__((ext_vector_type(4)));

typedef __attribute__((address_space(1))) void GV;   // global AS
typedef __attribute__((address_space(3))) void LV;   // LDS AS

#define QSCALE 0.04508422003f   // log2(e)/32  (folded into Q at GEMM1 epilogue)

__device__ __forceinline__ unsigned short f2bf(float f) {
    unsigned int u = __float_as_uint(f);
    u += 0x7fffu + ((u >> 16) & 1u);     // round-to-nearest-even
    return (unsigned short)(u >> 16);
}

__device__ __forceinline__ float ex2(float x) {
#if __has_builtin(__builtin_amdgcn_exp2f)
    return __builtin_amdgcn_exp2f(x);    // bare v_exp_f32, no libm fixup
#else
    return exp2f(x);
#endif
}

// ---------------------------------------------------------------- cast kernel
__global__ __launch_bounds__(256) void cast_f32_bf16(const float* __restrict__ in,
                                                     unsigned short* __restrict__ out) {
    int i = (blockIdx.x * 256 + threadIdx.x) * 4;
    float4 v = *(const float4*)(in + i);
    ushort4v o;
    o.x = f2bf(v.x); o.y = f2bf(v.y); o.z = f2bf(v.z); o.w = f2bf(v.w);
    *(ushort4v*)(out + i) = o;
}

// ---------------------------------------------------------------- GEMM (C = A * B^T), bf16 in, fp32 acc
// MODE 0: qkv scatter epilogue:
//   Q: bf16 [bh][n][64], pre-scaled by QSCALE
//   K: bf16 fragment-order (attn S^T B-operand reads, 16x16x32 bf16)
//   V: fp16 fragment-order with PERMUTED key axis matching the P register
//      packing for 16x16x32 f16 PV MFMAs (see attn kernel)
// MODE 1: fp32 out + bias epilogue
template<int MODE>
__global__ __launch_bounds__(256, 3)
void gemm_bt(const unsigned short* __restrict__ A,
             const unsigned short* __restrict__ B,
             unsigned short* __restrict__ Cq,
             unsigned short* __restrict__ Ck,
             unsigned short* __restrict__ Cv,
             const float* __restrict__ bias,
             float* __restrict__ Cout)
{
    __shared__ unsigned short As[128 * 32];
    __shared__ unsigned short Bs[128 * 32];
    const int tid  = threadIdx.x;
    const int lane = tid & 63;
    const int w    = tid >> 6;
    const int quad = lane >> 4;
    const int l15  = lane & 15;
    const int wm   = w >> 1, wn = w & 1;
    const int bm   = blockIdx.x, bn = blockIdx.y;

    const unsigned short* Arow = A + (size_t)bm * 128 * KDIM;
    const unsigned short* Brow = B + (size_t)bn * 128 * KDIM;

    const unsigned short* ga[2]; const unsigned short* gb[2];
    unsigned short* la[2];       unsigned short* lb[2];
#pragma unroll
    for (int i = 0; i < 2; ++i) {
        int j = ((w * 2 + i) << 6) + lane;
        int r = j >> 2;
        int c = (j & 3) ^ ((r >> 1) & 3);
        ga[i] = Arow + r * KDIM + c * 8;
        gb[i] = Brow + r * KDIM + c * 8;
        la[i] = (unsigned short*)As + ((w * 2 + i) << 9);
        lb[i] = (unsigned short*)Bs + ((w * 2 + i) << 9);
    }

    int achunk[4], bchunk[4];
#pragma unroll
    for (int t = 0; t < 4; ++t) {
        int ra = wm * 64 + t * 16 + l15;
        achunk[t] = (ra << 2) + (quad ^ ((ra >> 1) & 3));
        int rb = wn * 64 + t * 16 + l15;
        bchunk[t] = (rb << 2) + (quad ^ ((rb >> 1) & 3));
    }

    floatx4 acc[4][4];
#pragma unroll
    for (int mt = 0; mt < 4; ++mt)
#pragma unroll
        for (int nt = 0; nt < 4; ++nt)
            acc[mt][nt] = (floatx4){0.f, 0.f, 0.f, 0.f};

    for (int kt = 0; kt < KDIM / 32; ++kt) {
#pragma unroll
        for (int i = 0; i < 2; ++i) {
            __builtin_amdgcn_global_load_lds((GV*)(void*)(ga[i] + kt * 32), (LV*)(void*)la[i], 16, 0, 0);
            __builtin_amdgcn_global_load_lds((GV*)(void*)(gb[i] + kt * 32), (LV*)(void*)lb[i], 16, 0, 0);
        }
        __syncthreads();
        short8 af[4], bf[4];
#pragma unroll
        for (int t = 0; t < 4; ++t) {
            af[t] = *(const short8*)(As + (achunk[t] << 3));
            bf[t] = *(const short8*)(Bs + (bchunk[t] << 3));
        }
#pragma unroll
        for (int mt = 0; mt < 4; ++mt)
#pragma unroll
            for (int nt = 0; nt < 4; ++nt)
                acc[mt][nt] = __builtin_amdgcn_mfma_f32_16x16x32_bf16(af[mt], bf[nt], acc[mt][nt], 0, 0, 0);
        __syncthreads();
    }

    if (MODE == 0) {
        const int which = bn >> 3;  // 0=q 1=k 2=v
        unsigned short* dst = which == 0 ? Cq : (which == 1 ? Ck : Cv);
#pragma unroll
        for (int nt = 0; nt < 4; ++nt) {
            int e0   = ((bn & 7) << 7) + wn * 64 + nt * 16;
            int head = e0 >> 6;
            int hdi  = (e0 & 63) + l15;          // d / hd index in [0,64)
#pragma unroll
            for (int mt = 0; mt < 4; ++mt) {
#pragma unroll
                for (int r = 0; r < 4; ++r) {
                    int m = bm * 128 + wm * 64 + mt * 16 + quad * 4 + r;
                    int b = m >> 11, n = m & 2047;   // n = token = key
                    int bh = (b << 4) + head;
                    float val = acc[mt][nt][r];
                    if (which == 0) {
                        dst[((size_t)bh * SEQ + n) * HD + hdi] = f2bf(val * QSCALE);
                    } else if (which == 1) {
                        // K fragment-order (B-operand of 16x16x32 bf16)
                        size_t idx = (size_t)bh * 131072
                                   + (size_t)(n >> 7) * 8192
                                   + (size_t)((((n >> 4) & 7) * 2) + (hdi >> 5)) * 512
                                   + ((((hdi >> 3) & 3) * 16) + (n & 15)) * 8
                                   + (hdi & 7);
                        dst[idx] = f2bf(val);
                    } else {
                        // V fragment-order (B-operand of 16x16x32 f16, permuted keys):
                        // key = 32u + 16*(j>>2) + quad*4 + (j&3)
                        int nt7 = n & 127;
                        int u   = nt7 >> 5;
                        int k5  = nt7 & 31;
                        int c   = k5 & 15;
                        int q   = c >> 2;
                        int j   = ((k5 >> 4) << 2) | (c & 3);
                        size_t idx = (size_t)bh * 131072
                                   + (size_t)(n >> 7) * 8192
                                   + (size_t)(u * 4 + ((hdi >> 4) & 3)) * 512
                                   + (q * 16 + (hdi & 15)) * 8
                                   + j;
                        _Float16 hv = (_Float16)val;
                        dst[idx] = __builtin_bit_cast(unsigned short, hv);
                    }
                }
            }
        }
    } else {
#pragma unroll
        for (int nt = 0; nt < 4; ++nt) {
            int e = bn * 128 + wn * 64 + nt * 16 + l15;
            float bv = bias[e];
#pragma unroll
            for (int mt = 0; mt < 4; ++mt) {
#pragma unroll
                for (int r = 0; r < 4; ++r) {
                    int m = bm * 128 + wm * 64 + mt * 16 + quad * 4 + r;
                    Cout[(size_t)m * NDIM + e] = acc[mt][nt][r] + bv;
                }
            }
        }
    }
}

// ---------------------------------------------------------------- flash attention, v5.1
// - fragment-order K/V (zero addr VALU, zero conflicts)
// - register-prefetch of next K/V tile
// - raw v_exp_f32; l via ones-MFMA
// - PV on NATIVE 16x16x32_f16 (V key axis pre-permuted; half the PV MFMAs)
__global__ __launch_bounds__(256, 4)
void attn_fused(const unsigned short* __restrict__ qb,
                const unsigned short* __restrict__ kfrag,   // bf16 fragment-order
                const unsigned short* __restrict__ vfrag,   // fp16 fragment-order
                unsigned short* __restrict__ ob)            // bf16 [b][n][1024]
{
    __shared__ unsigned short Ks[8192];   // 128-key K tile (16 KB), fragment order
    __shared__ unsigned short Vs[8192];   // 128-key V tile (16 KB fp16), fragment order

    const int tid  = threadIdx.x;
    const int lane = tid & 63;
    const int w    = tid >> 6;
    const int quad = lane >> 4;
    const int l15  = lane & 15;

    const int bid  = blockIdx.x;
    const int xcd  = bid & 7;
    const int slot = bid >> 3;
    const int bh   = xcd * 8 + (slot >> 4);   // 8 bh per XCD
    const int q0   = (slot & 15) * 128;

    const unsigned short* Qb = qb    + (size_t)bh * SEQ * HD;
    const unsigned short* Kb = kfrag + (size_t)bh * 131072;
    const unsigned short* Vb = vfrag + (size_t)bh * 131072;

    // Q fragments (MFMA B operand): rows q0 + w*32 + qt*16 + l15 (pre-scaled by log2e/32)
    short8 qf[2][2];
#pragma unroll
    for (int qt = 0; qt < 2; ++qt)
#pragma unroll
        for (int ks = 0; ks < 2; ++ks)
            qf[qt][ks] = *(const short8*)(Qb + (size_t)(q0 + w * 32 + qt * 16 + l15) * HD + ks * 32 + quad * 8);

    floatx4 oacc[2][4];   // O[q=quad*4+r][hd=nt*16+l15]
    floatx4 lacc4[2];     // l[q=quad*4+r]
#pragma unroll
    for (int qt = 0; qt < 2; ++qt) {
#pragma unroll
        for (int nt = 0; nt < 4; ++nt) oacc[qt][nt] = (floatx4){0.f, 0.f, 0.f, 0.f};
        lacc4[qt] = (floatx4){0.f, 0.f, 0.f, 0.f};
    }
    half8 vones;
#pragma unroll
    for (int i = 0; i < 8; ++i) vones[i] = (_Float16)1.0f;

    // staging: tile = 1024 16B chunks; wave w handles chunks [w*256, w*256+256)
    const unsigned short* gk[4]; const unsigned short* gv[4];
    unsigned short* lk[4];       unsigned short* lv[4];
#pragma unroll
    for (int i = 0; i < 4; ++i) {
        int chunk = ((w * 4 + i) << 6) + lane;
        gk[i] = Kb + chunk * 8;
        gv[i] = Vb + chunk * 8;
        lk[i] = (unsigned short*)Ks + ((w * 4 + i) << 9) + lane * 8;
        lv[i] = (unsigned short*)Vs + ((w * 4 + i) << 9) + lane * 8;
    }

    // prefetch tile 0 into registers
    uint4v pk[4], pv[4];
#pragma unroll
    for (int i = 0; i < 4; ++i) {
        pk[i] = *(const uint4v*)gk[i];
        pv[i] = *(const uint4v*)gv[i];
    }

    for (int kt = 0; kt < 16; ++kt) {
        // commit prefetched tile to LDS
#pragma unroll
        for (int i = 0; i < 4; ++i) {
            *(uint4v*)lk[i] = pk[i];
            *(uint4v*)lv[i] = pv[i];
        }
        __syncthreads();
        // issue prefetch for next tile (lands during this tile's compute)
        if (kt < 15) {
#pragma unroll
            for (int i = 0; i < 4; ++i) {
                pk[i] = *(const uint4v*)(gk[i] + (kt + 1) * 8192);
                pv[i] = *(const uint4v*)(gv[i] + (kt + 1) * 8192);
            }
        }

        // ---- S^T = K * Q^T : lane holds S^T[key=ktile*16+quad*4+r][q=l15] (pre-scaled)
        floatx4 sacc[2][8];
#pragma unroll
        for (int qt = 0; qt < 2; ++qt)
#pragma unroll
            for (int nt = 0; nt < 8; ++nt) sacc[qt][nt] = (floatx4){0.f, 0.f, 0.f, 0.f};
#pragma unroll
        for (int ks = 0; ks < 2; ++ks) {
#pragma unroll
            for (int nt = 0; nt < 8; ++nt) {
                short8 kf = *(const short8*)(Ks + (nt * 2 + ks) * 512 + lane * 8);
                sacc[0][nt] = __builtin_amdgcn_mfma_f32_16x16x32_bf16(kf, qf[0][ks], sacc[0][nt], 0, 0, 0);
                sacc[1][nt] = __builtin_amdgcn_mfma_f32_16x16x32_bf16(kf, qf[1][ks], sacc[1][nt], 0, 0, 0);
            }
        }

        // ---- softmax + PV over 32-key groups (native 16x16x32 f16)
#pragma unroll
        for (int u = 0; u < 4; ++u) {
            half8 pf[2];
#pragma unroll
            for (int qt = 0; qt < 2; ++qt) {
                floatx4 s0 = sacc[qt][2 * u];
                floatx4 s1 = sacc[qt][2 * u + 1];
                fp16x2 c0 = __builtin_amdgcn_cvt_pkrtz(ex2(s0[0]), ex2(s0[1]));
                fp16x2 c1 = __builtin_amdgcn_cvt_pkrtz(ex2(s0[2]), ex2(s0[3]));
                fp16x2 c2 = __builtin_amdgcn_cvt_pkrtz(ex2(s1[0]), ex2(s1[1]));
                fp16x2 c3 = __builtin_amdgcn_cvt_pkrtz(ex2(s1[2]), ex2(s1[3]));
                uint4v uu;
                uu.x = __builtin_bit_cast(unsigned int, c0);
                uu.y = __builtin_bit_cast(unsigned int, c1);
                uu.z = __builtin_bit_cast(unsigned int, c2);
                uu.w = __builtin_bit_cast(unsigned int, c3);
                pf[qt] = __builtin_bit_cast(half8, uu);
                // l row-sum via ones-MFMA (aligned with oacc rows)
                lacc4[qt] = __builtin_amdgcn_mfma_f32_16x16x32_f16(pf[qt], vones, lacc4[qt], 0, 0, 0);
            }
#pragma unroll
            for (int nt = 0; nt < 4; ++nt) {
                uint4v vv = *(const uint4v*)((const unsigned short*)Vs + (u * 4 + nt) * 512 + lane * 8);
                half8 vf = __builtin_bit_cast(half8, vv);
                oacc[0][nt] = __builtin_amdgcn_mfma_f32_16x16x32_f16(pf[0], vf, oacc[0][nt], 0, 0, 0);
                oacc[1][nt] = __builtin_amdgcn_mfma_f32_16x16x32_f16(pf[1], vf, oacc[1][nt], 0, 0, 0);
            }
        }
        __syncthreads();
    }

    // ---- epilogue: O /= l, write bf16
    const int b = bh >> 4, h = bh & 15;
#pragma unroll
    for (int qt = 0; qt < 2; ++qt) {
#pragma unroll
        for (int r = 0; r < 4; ++r) {
            float inv = 1.f / lacc4[qt][r];
            int n = q0 + w * 32 + qt * 16 + quad * 4 + r;
            size_t rowoff = ((size_t)b * SEQ + n) * NDIM + h * HD;
#pragma unroll
            for (int nt = 0; nt < 4; ++nt)
                ob[rowoff + nt * 16 + l15] = f2bf(oacc[qt][nt][r] * inv);
        }
    }
}

// ---------------------------------------------------------------- launch
extern "C" void kernel_launch(void* const* d_in, const int* in_sizes, int n_in,
                              void* d_out, int out_size, void* d_ws, size_t ws_size,
                              hipStream_t stream)
{
    (void)in_sizes; (void)n_in; (void)out_size; (void)ws_size;
    const float* x    = (const float*)d_in[0];
    const float* wqkv = (const float*)d_in[1];
    const float* wout = (const float*)d_in[2];
    const float* bout = (const float*)d_in[3];
    float* out = (float*)d_out;

    unsigned short* xb    = (unsigned short*)d_ws;
    unsigned short* wqkvb = xb    + 8388608;
    unsigned short* woutb = wqkvb + 3145728;
    unsigned short* qbuf  = woutb + 1048576;
    unsigned short* kbuf  = qbuf  + 8388608;
    unsigned short* vbuf  = kbuf  + 8388608;
    unsigned short* obuf  = vbuf  + 8388608;

    cast_f32_bf16<<<8192, 256, 0, stream>>>(x, xb);
    cast_f32_bf16<<<3072, 256, 0, stream>>>(wqkv, wqkvb);
    cast_f32_bf16<<<1024, 256, 0, stream>>>(wout, woutb);

    gemm_bt<0><<<dim3(64, 24), 256, 0, stream>>>(xb, wqkvb, qbuf, kbuf, vbuf, nullptr, nullptr);
    attn_fused<<<1024, 256, 0, stream>>>(qbuf, kbuf, vbuf, obuf);
    gemm_bt<1><<<dim3(64, 8), 256, 0, stream>>>(obuf, woutb, nullptr, nullptr, nullptr, bout, out);
}

// Round 9
// 261.013 us; speedup vs baseline: 1.1303x; 1.1303x over previous
//
#include <hip/hip_runtime.h>
#include <stdint.h>

#define SEQ   2048
#define NDIM  1024
#define NH    16
#define HD    64
#define KDIM  1024

typedef short  short8  __attribute__((ext_vector_type(8)));
typedef float  floatx4 __attribute__((ext_vector_type(4)));
typedef unsigned short ushort4v __attribute__((ext_vector_type(4)));
typedef _Float16 half8 __attribute__((ext_vector_type(8)));
typedef __fp16  fp16x2 __attribute__((ext_vector_type(2)));
typedef unsigned int uint2v __attribute__((ext_vector_type(2)));
typedef unsigned int uint4v __attribute__((ext_vector_type(4)));

typedef __attribute__((address_space(1))) void GV;   // global AS
typedef __attribute__((address_space(3))) void LV;   // LDS AS

#define QSCALE 0.04508422003f   // log2(e)/32  (folded into Q at GEMM1 epilogue)

__device__ __forceinline__ unsigned short f2bf(float f) {
    unsigned int u = __float_as_uint(f);
    u += 0x7fffu + ((u >> 16) & 1u);     // round-to-nearest-even
    return (unsigned short)(u >> 16);
}

__device__ __forceinline__ float ex2(float x) {
#if __has_builtin(__builtin_amdgcn_exp2f)
    return __builtin_amdgcn_exp2f(x);    // bare v_exp_f32, no libm fixup
#else
    return exp2f(x);
#endif
}

// ---------------------------------------------------------------- cast kernel
__global__ __launch_bounds__(256) void cast_f32_bf16(const float* __restrict__ in,
                                                     unsigned short* __restrict__ out) {
    int i = (blockIdx.x * 256 + threadIdx.x) * 4;
    float4 v = *(const float4*)(in + i);
    ushort4v o;
    o.x = f2bf(v.x); o.y = f2bf(v.y); o.z = f2bf(v.z); o.w = f2bf(v.w);
    *(ushort4v*)(out + i) = o;
}

// ---------------------------------------------------------------- GEMM (C = A * B^T), bf16 in, fp32 acc
// MODE 0: qkv scatter epilogue:
//   Q: bf16 [bh][n][64], pre-scaled by QSCALE
//   K: bf16 fragment-order (attn S^T B-operand reads, 16x16x32 bf16)
//   V: fp16 fragment-order, permuted key axis matching P packing for
//      16x16x32 f16 PV MFMAs; 4 r-values stored as one 8B chunk
// MODE 1: fp32 out + bias epilogue
template<int MODE>
__global__ __launch_bounds__(256, 3)
void gemm_bt(const unsigned short* __restrict__ A,
             const unsigned short* __restrict__ B,
             unsigned short* __restrict__ Cq,
             unsigned short* __restrict__ Ck,
             unsigned short* __restrict__ Cv,
             const float* __restrict__ bias,
             float* __restrict__ Cout)
{
    __shared__ unsigned short As[128 * 32];
    __shared__ unsigned short Bs[128 * 32];
    const int tid  = threadIdx.x;
    const int lane = tid & 63;
    const int w    = tid >> 6;
    const int quad = lane >> 4;
    const int l15  = lane & 15;
    const int wm   = w >> 1, wn = w & 1;
    const int bm   = blockIdx.x, bn = blockIdx.y;

    const unsigned short* Arow = A + (size_t)bm * 128 * KDIM;
    const unsigned short* Brow = B + (size_t)bn * 128 * KDIM;

    const unsigned short* ga[2]; const unsigned short* gb[2];
    unsigned short* la[2];       unsigned short* lb[2];
#pragma unroll
    for (int i = 0; i < 2; ++i) {
        int j = ((w * 2 + i) << 6) + lane;
        int r = j >> 2;
        int c = (j & 3) ^ ((r >> 1) & 3);
        ga[i] = Arow + r * KDIM + c * 8;
        gb[i] = Brow + r * KDIM + c * 8;
        la[i] = (unsigned short*)As + ((w * 2 + i) << 9);
        lb[i] = (unsigned short*)Bs + ((w * 2 + i) << 9);
    }

    int achunk[4], bchunk[4];
#pragma unroll
    for (int t = 0; t < 4; ++t) {
        int ra = wm * 64 + t * 16 + l15;
        achunk[t] = (ra << 2) + (quad ^ ((ra >> 1) & 3));
        int rb = wn * 64 + t * 16 + l15;
        bchunk[t] = (rb << 2) + (quad ^ ((rb >> 1) & 3));
    }

    floatx4 acc[4][4];
#pragma unroll
    for (int mt = 0; mt < 4; ++mt)
#pragma unroll
        for (int nt = 0; nt < 4; ++nt)
            acc[mt][nt] = (floatx4){0.f, 0.f, 0.f, 0.f};

    for (int kt = 0; kt < KDIM / 32; ++kt) {
#pragma unroll
        for (int i = 0; i < 2; ++i) {
            __builtin_amdgcn_global_load_lds((GV*)(void*)(ga[i] + kt * 32), (LV*)(void*)la[i], 16, 0, 0);
            __builtin_amdgcn_global_load_lds((GV*)(void*)(gb[i] + kt * 32), (LV*)(void*)lb[i], 16, 0, 0);
        }
        __syncthreads();
        short8 af[4], bf[4];
#pragma unroll
        for (int t = 0; t < 4; ++t) {
            af[t] = *(const short8*)(As + (achunk[t] << 3));
            bf[t] = *(const short8*)(Bs + (bchunk[t] << 3));
        }
#pragma unroll
        for (int mt = 0; mt < 4; ++mt)
#pragma unroll
            for (int nt = 0; nt < 4; ++nt)
                acc[mt][nt] = __builtin_amdgcn_mfma_f32_16x16x32_bf16(af[mt], bf[nt], acc[mt][nt], 0, 0, 0);
        __syncthreads();
    }

    if (MODE == 0) {
        const int which = bn >> 3;  // 0=q 1=k 2=v
        unsigned short* dst = which == 0 ? Cq : (which == 1 ? Ck : Cv);
        if (which == 2) {
            // V: one 8B store per (nt,mt) — r=0..3 are consecutive j
#pragma unroll
            for (int nt = 0; nt < 4; ++nt) {
                int e0   = ((bn & 7) << 7) + wn * 64 + nt * 16;
                int head = e0 >> 6;
                int hdi  = (e0 & 63) + l15;
#pragma unroll
                for (int mt = 0; mt < 4; ++mt) {
                    int n0 = bm * 128 + wm * 64 + mt * 16 + quad * 4;  // r=0 token (mod use below)
                    int b  = n0 >> 11;
                    int n  = n0 & 2047;
                    int bh = (b << 4) + head;
                    int u  = (n & 127) >> 5;
                    size_t base = (size_t)bh * 131072
                                + (size_t)(n >> 7) * 8192
                                + (size_t)(u * 4 + ((hdi >> 4) & 3)) * 512
                                + (quad * 16 + (hdi & 15)) * 8
                                + ((mt & 1) << 2);
                    fp16x2 p01 = __builtin_amdgcn_cvt_pkrtz(acc[mt][nt][0], acc[mt][nt][1]);
                    fp16x2 p23 = __builtin_amdgcn_cvt_pkrtz(acc[mt][nt][2], acc[mt][nt][3]);
                    uint2v st;
                    st.x = __builtin_bit_cast(unsigned int, p01);
                    st.y = __builtin_bit_cast(unsigned int, p23);
                    *(uint2v*)(dst + base) = st;
                }
            }
        } else {
#pragma unroll
            for (int nt = 0; nt < 4; ++nt) {
                int e0   = ((bn & 7) << 7) + wn * 64 + nt * 16;
                int head = e0 >> 6;
                int hdi  = (e0 & 63) + l15;
#pragma unroll
                for (int mt = 0; mt < 4; ++mt) {
#pragma unroll
                    for (int r = 0; r < 4; ++r) {
                        int m = bm * 128 + wm * 64 + mt * 16 + quad * 4 + r;
                        int b = m >> 11, n = m & 2047;
                        int bh = (b << 4) + head;
                        float val = acc[mt][nt][r];
                        if (which == 0) {
                            dst[((size_t)bh * SEQ + n) * HD + hdi] = f2bf(val * QSCALE);
                        } else {
                            size_t idx = (size_t)bh * 131072
                                       + (size_t)(n >> 7) * 8192
                                       + (size_t)((((n >> 4) & 7) * 2) + (hdi >> 5)) * 512
                                       + ((((hdi >> 3) & 3) * 16) + (n & 15)) * 8
                                       + (hdi & 7);
                            dst[idx] = f2bf(val);
                        }
                    }
                }
            }
        }
    } else {
#pragma unroll
        for (int nt = 0; nt < 4; ++nt) {
            int e = bn * 128 + wn * 64 + nt * 16 + l15;
            float bv = bias[e];
#pragma unroll
            for (int mt = 0; mt < 4; ++mt) {
#pragma unroll
                for (int r = 0; r < 4; ++r) {
                    int m = bm * 128 + wm * 64 + mt * 16 + quad * 4 + r;
                    Cout[(size_t)m * NDIM + e] = acc[mt][nt][r] + bv;
                }
            }
        }
    }
}

// ---------------------------------------------------------------- flash attention, v6
// True async double-buffered staging: 64-key subtiles (8KB K + 8KB V),
// one barrier per subtile; DMA for t+1 issued right after barrier t so the
// compiler's vmcnt(0)-before-barrier drain has a full compute phase to land.
// PV on native 16x16x32_f16 (V pre-permuted); l via ones-MFMA; raw v_exp.
__global__ __launch_bounds__(256, 4)
void attn_fused(const unsigned short* __restrict__ qb,
                const unsigned short* __restrict__ kfrag,   // bf16 fragment-order
                const unsigned short* __restrict__ vfrag,   // fp16 fragment-order
                unsigned short* __restrict__ ob)            // bf16 [b][n][1024]
{
    __shared__ unsigned short Ks[2][4096];   // 64-key K subtile x2 (16 KB)
    __shared__ unsigned short Vs[2][4096];   // 64-key V subtile x2 (16 KB)

    const int tid  = threadIdx.x;
    const int lane = tid & 63;
    const int w    = tid >> 6;
    const int quad = lane >> 4;
    const int l15  = lane & 15;

    const int bid  = blockIdx.x;
    const int xcd  = bid & 7;
    const int slot = bid >> 3;
    const int bh   = xcd * 8 + (slot >> 4);   // 8 bh per XCD
    const int q0   = (slot & 15) * 128;

    const unsigned short* Qb = qb    + (size_t)bh * SEQ * HD;
    const unsigned short* Kb = kfrag + (size_t)bh * 131072;
    const unsigned short* Vb = vfrag + (size_t)bh * 131072;

    // Q fragments (MFMA B operand): rows q0 + w*32 + qt*16 + l15 (pre-scaled)
    short8 qf[2][2];
#pragma unroll
    for (int qt = 0; qt < 2; ++qt)
#pragma unroll
        for (int ks = 0; ks < 2; ++ks)
            qf[qt][ks] = *(const short8*)(Qb + (size_t)(q0 + w * 32 + qt * 16 + l15) * HD + ks * 32 + quad * 8);

    floatx4 oacc[2][4];   // O[q=quad*4+r][hd=nt*16+l15]
    floatx4 lacc4[2];     // l[q=quad*4+r]
#pragma unroll
    for (int qt = 0; qt < 2; ++qt) {
#pragma unroll
        for (int nt = 0; nt < 4; ++nt) oacc[qt][nt] = (floatx4){0.f, 0.f, 0.f, 0.f};
        lacc4[qt] = (floatx4){0.f, 0.f, 0.f, 0.f};
    }
    half8 vones;
#pragma unroll
    for (int i = 0; i < 8; ++i) vones[i] = (_Float16)1.0f;

    // staging: subtile = 4096 shorts K + 4096 shorts V = 1024 16B chunks total;
    // wave w handles K chunks [w*128,w*128+128) and same for V (2 DMA each)
    const unsigned short* gk[2]; const unsigned short* gv[2];
    unsigned short* lk[2][2];    unsigned short* lv[2][2];
#pragma unroll
    for (int i = 0; i < 2; ++i) {
        int off = (((w * 2 + i) << 6) + lane) * 8;
        gk[i] = Kb + off;
        gv[i] = Vb + off;
#pragma unroll
        for (int b = 0; b < 2; ++b) {
            lk[b][i] = &Ks[b][(w * 2 + i) << 9];
            lv[b][i] = &Vs[b][(w * 2 + i) << 9];
        }
    }

    // prologue: DMA subtile 0 into buffer 0
#pragma unroll
    for (int i = 0; i < 2; ++i) {
        __builtin_amdgcn_global_load_lds((GV*)(void*)gk[i], (LV*)(void*)lk[0][i], 16, 0, 0);
        __builtin_amdgcn_global_load_lds((GV*)(void*)gv[i], (LV*)(void*)lv[0][i], 16, 0, 0);
    }

    for (int t = 0; t < 32; ++t) {
        const int buf = t & 1;
        __syncthreads();   // vmcnt(0): DMA for buf done; lgkmcnt: prev reads done
        if (t < 31) {
#pragma unroll
            for (int i = 0; i < 2; ++i) {
                __builtin_amdgcn_global_load_lds((GV*)(void*)(gk[i] + (t + 1) * 4096), (LV*)(void*)lk[buf ^ 1][i], 16, 0, 0);
                __builtin_amdgcn_global_load_lds((GV*)(void*)(gv[i] + (t + 1) * 4096), (LV*)(void*)lv[buf ^ 1][i], 16, 0, 0);
            }
        }
        const unsigned short* KsB = Ks[buf];
        const unsigned short* VsB = Vs[buf];

        // ---- S^T = K * Q^T over 64 keys: lane holds S^T[key=nt*16+quad*4+r][q=l15]
        floatx4 sacc[2][4];
#pragma unroll
        for (int qt = 0; qt < 2; ++qt)
#pragma unroll
            for (int nt = 0; nt < 4; ++nt) sacc[qt][nt] = (floatx4){0.f, 0.f, 0.f, 0.f};
#pragma unroll
        for (int ks = 0; ks < 2; ++ks) {
#pragma unroll
            for (int nt = 0; nt < 4; ++nt) {
                short8 kf = *(const short8*)(KsB + (nt * 2 + ks) * 512 + lane * 8);
                sacc[0][nt] = __builtin_amdgcn_mfma_f32_16x16x32_bf16(kf, qf[0][ks], sacc[0][nt], 0, 0, 0);
                sacc[1][nt] = __builtin_amdgcn_mfma_f32_16x16x32_bf16(kf, qf[1][ks], sacc[1][nt], 0, 0, 0);
            }
        }

        // ---- softmax + PV over 32-key groups (native 16x16x32 f16)
#pragma unroll
        for (int u = 0; u < 2; ++u) {
            half8 pf[2];
#pragma unroll
            for (int qt = 0; qt < 2; ++qt) {
                floatx4 s0 = sacc[qt][2 * u];
                floatx4 s1 = sacc[qt][2 * u + 1];
                fp16x2 c0 = __builtin_amdgcn_cvt_pkrtz(ex2(s0[0]), ex2(s0[1]));
                fp16x2 c1 = __builtin_amdgcn_cvt_pkrtz(ex2(s0[2]), ex2(s0[3]));
                fp16x2 c2 = __builtin_amdgcn_cvt_pkrtz(ex2(s1[0]), ex2(s1[1]));
                fp16x2 c3 = __builtin_amdgcn_cvt_pkrtz(ex2(s1[2]), ex2(s1[3]));
                uint4v uu;
                uu.x = __builtin_bit_cast(unsigned int, c0);
                uu.y = __builtin_bit_cast(unsigned int, c1);
                uu.z = __builtin_bit_cast(unsigned int, c2);
                uu.w = __builtin_bit_cast(unsigned int, c3);
                pf[qt] = __builtin_bit_cast(half8, uu);
                lacc4[qt] = __builtin_amdgcn_mfma_f32_16x16x32_f16(pf[qt], vones, lacc4[qt], 0, 0, 0);
            }
#pragma unroll
            for (int nt = 0; nt < 4; ++nt) {
                uint4v vv = *(const uint4v*)(VsB + (u * 4 + nt) * 512 + lane * 8);
                half8 vf = __builtin_bit_cast(half8, vv);
                oacc[0][nt] = __builtin_amdgcn_mfma_f32_16x16x32_f16(pf[0], vf, oacc[0][nt], 0, 0, 0);
                oacc[1][nt] = __builtin_amdgcn_mfma_f32_16x16x32_f16(pf[1], vf, oacc[1][nt], 0, 0, 0);
            }
        }
    }

    // ---- epilogue: O /= l, write bf16
    const int b = bh >> 4, h = bh & 15;
#pragma unroll
    for (int qt = 0; qt < 2; ++qt) {
#pragma unroll
        for (int r = 0; r < 4; ++r) {
            float inv = 1.f / lacc4[qt][r];
            int n = q0 + w * 32 + qt * 16 + quad * 4 + r;
            size_t rowoff = ((size_t)b * SEQ + n) * NDIM + h * HD;
#pragma unroll
            for (int nt = 0; nt < 4; ++nt)
                ob[rowoff + nt * 16 + l15] = f2bf(oacc[qt][nt][r] * inv);
        }
    }
}

// ---------------------------------------------------------------- launch
extern "C" void kernel_launch(void* const* d_in, const int* in_sizes, int n_in,
                              void* d_out, int out_size, void* d_ws, size_t ws_size,
                              hipStream_t stream)
{
    (void)in_sizes; (void)n_in; (void)out_size; (void)ws_size;
    const float* x    = (const float*)d_in[0];
    const float* wqkv = (const float*)d_in[1];
    const float* wout = (const float*)d_in[2];
    const float* bout = (const float*)d_in[3];
    float* out = (float*)d_out;

    unsigned short* xb    = (unsigned short*)d_ws;
    unsigned short* wqkvb = xb    + 8388608;
    unsigned short* woutb = wqkvb + 3145728;
    unsigned short* qbuf  = woutb + 1048576;
    unsigned short* kbuf  = qbuf  + 8388608;
    unsigned short* vbuf  = kbuf  + 8388608;
    unsigned short* obuf  = vbuf  + 8388608;

    cast_f32_bf16<<<8192, 256, 0, stream>>>(x, xb);
    cast_f32_bf16<<<3072, 256, 0, stream>>>(wqkv, wqkvb);
    cast_f32_bf16<<<1024, 256, 0, stream>>>(wout, woutb);

    gemm_bt<0><<<dim3(64, 24), 256, 0, stream>>>(xb, wqkvb, qbuf, kbuf, vbuf, nullptr, nullptr);
    attn_fused<<<1024, 256, 0, stream>>>(qbuf, kbuf, vbuf, obuf);
    gemm_bt<1><<<dim3(64, 8), 256, 0, stream>>>(obuf, woutb, nullptr, nullptr, nullptr, bout, out);
}

// Round 10
// 255.190 us; speedup vs baseline: 1.1561x; 1.0228x over previous
//
#include <hip/hip_runtime.h>
#include <stdint.h>

#define SEQ   2048
#define NDIM  1024
#define NH    16
#define HD    64
#define KDIM  1024

typedef short  short8  __attribute__((ext_vector_type(8)));
typedef float  floatx4 __attribute__((ext_vector_type(4)));
typedef unsigned short ushort4v __attribute__((ext_vector_type(4)));
typedef _Float16 half8 __attribute__((ext_vector_type(8)));
typedef __fp16  fp16x2 __attribute__((ext_vector_type(2)));
typedef unsigned int uint2v __attribute__((ext_vector_type(2)));
typedef unsigned int uint4v __attribute__((ext_vector_type(4)));

typedef __attribute__((address_space(1))) void GV;   // global AS
typedef __attribute__((address_space(3))) void LV;   // LDS AS

#define QSCALE 0.04508422003f   // log2(e)/32  (folded into Q at GEMM1 epilogue)

__device__ __forceinline__ unsigned short f2bf(float f) {
    unsigned int u = __float_as_uint(f);
    u += 0x7fffu + ((u >> 16) & 1u);     // round-to-nearest-even
    return (unsigned short)(u >> 16);
}

__device__ __forceinline__ float ex2(float x) {
#if __has_builtin(__builtin_amdgcn_exp2f)
    return __builtin_amdgcn_exp2f(x);    // bare v_exp_f32, no libm fixup
#else
    return exp2f(x);
#endif
}

// ---------------------------------------------------------------- cast kernel
__global__ __launch_bounds__(256) void cast_f32_bf16(const float* __restrict__ in,
                                                     unsigned short* __restrict__ out) {
    int i = (blockIdx.x * 256 + threadIdx.x) * 4;
    float4 v = *(const float4*)(in + i);
    ushort4v o;
    o.x = f2bf(v.x); o.y = f2bf(v.y); o.z = f2bf(v.z); o.w = f2bf(v.w);
    *(ushort4v*)(out + i) = o;
}

// ---------------------------------------------------------------- GEMM (C = A * B^T), bf16 in, fp32 acc
// v2: async double-buffered staging — ONE barrier per K-tile; DMA for tile
// t+1 issued right after barrier t so the vmcnt(0) drain at barrier t+1
// waits on a load that had a full compute phase to land.
// MODE 0: qkv scatter epilogue (Q pre-scaled; K/V in attn fragment order)
// MODE 1: fp32 out + bias epilogue
template<int MODE>
__global__ __launch_bounds__(256, 3)
void gemm_bt(const unsigned short* __restrict__ A,
             const unsigned short* __restrict__ B,
             unsigned short* __restrict__ Cq,
             unsigned short* __restrict__ Ck,
             unsigned short* __restrict__ Cv,
             const float* __restrict__ bias,
             float* __restrict__ Cout)
{
    __shared__ unsigned short As[2][4096];
    __shared__ unsigned short Bs[2][4096];
    const int tid  = threadIdx.x;
    const int lane = tid & 63;
    const int w    = tid >> 6;
    const int quad = lane >> 4;
    const int l15  = lane & 15;
    const int wm   = w >> 1, wn = w & 1;
    const int bm   = blockIdx.x, bn = blockIdx.y;

    const unsigned short* Arow = A + (size_t)bm * 128 * KDIM;
    const unsigned short* Brow = B + (size_t)bn * 128 * KDIM;

    const unsigned short* ga[2]; const unsigned short* gb[2];
    unsigned short* la[2][2];    unsigned short* lb[2][2];
#pragma unroll
    for (int i = 0; i < 2; ++i) {
        int j = ((w * 2 + i) << 6) + lane;
        int r = j >> 2;
        int c = (j & 3) ^ ((r >> 1) & 3);
        ga[i] = Arow + r * KDIM + c * 8;
        gb[i] = Brow + r * KDIM + c * 8;
#pragma unroll
        for (int b = 0; b < 2; ++b) {
            la[b][i] = &As[b][(w * 2 + i) << 9];
            lb[b][i] = &Bs[b][(w * 2 + i) << 9];
        }
    }

    int achunk[4], bchunk[4];
#pragma unroll
    for (int t = 0; t < 4; ++t) {
        int ra = wm * 64 + t * 16 + l15;
        achunk[t] = (ra << 2) + (quad ^ ((ra >> 1) & 3));
        int rb = wn * 64 + t * 16 + l15;
        bchunk[t] = (rb << 2) + (quad ^ ((rb >> 1) & 3));
    }

    floatx4 acc[4][4];
#pragma unroll
    for (int mt = 0; mt < 4; ++mt)
#pragma unroll
        for (int nt = 0; nt < 4; ++nt)
            acc[mt][nt] = (floatx4){0.f, 0.f, 0.f, 0.f};

    // prologue: DMA K-tile 0 into buffer 0
#pragma unroll
    for (int i = 0; i < 2; ++i) {
        __builtin_amdgcn_global_load_lds((GV*)(void*)ga[i], (LV*)(void*)la[0][i], 16, 0, 0);
        __builtin_amdgcn_global_load_lds((GV*)(void*)gb[i], (LV*)(void*)lb[0][i], 16, 0, 0);
    }

    for (int kt = 0; kt < KDIM / 32; ++kt) {
        const int buf = kt & 1;
        __syncthreads();   // drains DMA for buf (issued a full compute phase ago)
        if (kt < KDIM / 32 - 1) {
#pragma unroll
            for (int i = 0; i < 2; ++i) {
                __builtin_amdgcn_global_load_lds((GV*)(void*)(ga[i] + (kt + 1) * 32), (LV*)(void*)la[buf ^ 1][i], 16, 0, 0);
                __builtin_amdgcn_global_load_lds((GV*)(void*)(gb[i] + (kt + 1) * 32), (LV*)(void*)lb[buf ^ 1][i], 16, 0, 0);
            }
        }
        short8 af[4], bf[4];
#pragma unroll
        for (int t = 0; t < 4; ++t) {
            af[t] = *(const short8*)(&As[buf][0] + (achunk[t] << 3));
            bf[t] = *(const short8*)(&Bs[buf][0] + (bchunk[t] << 3));
        }
#pragma unroll
        for (int mt = 0; mt < 4; ++mt)
#pragma unroll
            for (int nt = 0; nt < 4; ++nt)
                acc[mt][nt] = __builtin_amdgcn_mfma_f32_16x16x32_bf16(af[mt], bf[nt], acc[mt][nt], 0, 0, 0);
    }

    if (MODE == 0) {
        const int which = bn >> 3;  // 0=q 1=k 2=v
        unsigned short* dst = which == 0 ? Cq : (which == 1 ? Ck : Cv);
        if (which == 2) {
            // V: one 8B store per (nt,mt) — r=0..3 are consecutive j
#pragma unroll
            for (int nt = 0; nt < 4; ++nt) {
                int e0   = ((bn & 7) << 7) + wn * 64 + nt * 16;
                int head = e0 >> 6;
                int hdi  = (e0 & 63) + l15;
#pragma unroll
                for (int mt = 0; mt < 4; ++mt) {
                    int n0 = bm * 128 + wm * 64 + mt * 16 + quad * 4;
                    int b  = n0 >> 11;
                    int n  = n0 & 2047;
                    int bh = (b << 4) + head;
                    int u  = (n & 127) >> 5;
                    size_t base = (size_t)bh * 131072
                                + (size_t)(n >> 7) * 8192
                                + (size_t)(u * 4 + ((hdi >> 4) & 3)) * 512
                                + (quad * 16 + (hdi & 15)) * 8
                                + ((mt & 1) << 2);
                    fp16x2 p01 = __builtin_amdgcn_cvt_pkrtz(acc[mt][nt][0], acc[mt][nt][1]);
                    fp16x2 p23 = __builtin_amdgcn_cvt_pkrtz(acc[mt][nt][2], acc[mt][nt][3]);
                    uint2v st;
                    st.x = __builtin_bit_cast(unsigned int, p01);
                    st.y = __builtin_bit_cast(unsigned int, p23);
                    *(uint2v*)(dst + base) = st;
                }
            }
        } else {
#pragma unroll
            for (int nt = 0; nt < 4; ++nt) {
                int e0   = ((bn & 7) << 7) + wn * 64 + nt * 16;
                int head = e0 >> 6;
                int hdi  = (e0 & 63) + l15;
#pragma unroll
                for (int mt = 0; mt < 4; ++mt) {
#pragma unroll
                    for (int r = 0; r < 4; ++r) {
                        int m = bm * 128 + wm * 64 + mt * 16 + quad * 4 + r;
                        int b = m >> 11, n = m & 2047;
                        int bh = (b << 4) + head;
                        float val = acc[mt][nt][r];
                        if (which == 0) {
                            dst[((size_t)bh * SEQ + n) * HD + hdi] = f2bf(val * QSCALE);
                        } else {
                            size_t idx = (size_t)bh * 131072
                                       + (size_t)(n >> 7) * 8192
                                       + (size_t)((((n >> 4) & 7) * 2) + (hdi >> 5)) * 512
                                       + ((((hdi >> 3) & 3) * 16) + (n & 15)) * 8
                                       + (hdi & 7);
                            dst[idx] = f2bf(val);
                        }
                    }
                }
            }
        }
    } else {
#pragma unroll
        for (int nt = 0; nt < 4; ++nt) {
            int e = bn * 128 + wn * 64 + nt * 16 + l15;
            float bv = bias[e];
#pragma unroll
            for (int mt = 0; mt < 4; ++mt) {
#pragma unroll
                for (int r = 0; r < 4; ++r) {
                    int m = bm * 128 + wm * 64 + mt * 16 + quad * 4 + r;
                    Cout[(size_t)m * NDIM + e] = acc[mt][nt][r] + bv;
                }
            }
        }
    }
}

// ---------------------------------------------------------------- flash attention, v6 (unchanged)
// True async double-buffered staging: 64-key subtiles (8KB K + 8KB V),
// one barrier per subtile. PV on native 16x16x32_f16 (V pre-permuted);
// l via ones-MFMA; raw v_exp.
__global__ __launch_bounds__(256, 4)
void attn_fused(const unsigned short* __restrict__ qb,
                const unsigned short* __restrict__ kfrag,   // bf16 fragment-order
                const unsigned short* __restrict__ vfrag,   // fp16 fragment-order
                unsigned short* __restrict__ ob)            // bf16 [b][n][1024]
{
    __shared__ unsigned short Ks[2][4096];   // 64-key K subtile x2 (16 KB)
    __shared__ unsigned short Vs[2][4096];   // 64-key V subtile x2 (16 KB)

    const int tid  = threadIdx.x;
    const int lane = tid & 63;
    const int w    = tid >> 6;
    const int quad = lane >> 4;
    const int l15  = lane & 15;

    const int bid  = blockIdx.x;
    const int xcd  = bid & 7;
    const int slot = bid >> 3;
    const int bh   = xcd * 8 + (slot >> 4);   // 8 bh per XCD
    const int q0   = (slot & 15) * 128;

    const unsigned short* Qb = qb    + (size_t)bh * SEQ * HD;
    const unsigned short* Kb = kfrag + (size_t)bh * 131072;
    const unsigned short* Vb = vfrag + (size_t)bh * 131072;

    // Q fragments (MFMA B operand): rows q0 + w*32 + qt*16 + l15 (pre-scaled)
    short8 qf[2][2];
#pragma unroll
    for (int qt = 0; qt < 2; ++qt)
#pragma unroll
        for (int ks = 0; ks < 2; ++ks)
            qf[qt][ks] = *(const short8*)(Qb + (size_t)(q0 + w * 32 + qt * 16 + l15) * HD + ks * 32 + quad * 8);

    floatx4 oacc[2][4];   // O[q=quad*4+r][hd=nt*16+l15]
    floatx4 lacc4[2];     // l[q=quad*4+r]
#pragma unroll
    for (int qt = 0; qt < 2; ++qt) {
#pragma unroll
        for (int nt = 0; nt < 4; ++nt) oacc[qt][nt] = (floatx4){0.f, 0.f, 0.f, 0.f};
        lacc4[qt] = (floatx4){0.f, 0.f, 0.f, 0.f};
    }
    half8 vones;
#pragma unroll
    for (int i = 0; i < 8; ++i) vones[i] = (_Float16)1.0f;

    const unsigned short* gk[2]; const unsigned short* gv[2];
    unsigned short* lk[2][2];    unsigned short* lv[2][2];
#pragma unroll
    for (int i = 0; i < 2; ++i) {
        int off = (((w * 2 + i) << 6) + lane) * 8;
        gk[i] = Kb + off;
        gv[i] = Vb + off;
#pragma unroll
        for (int b = 0; b < 2; ++b) {
            lk[b][i] = &Ks[b][(w * 2 + i) << 9];
            lv[b][i] = &Vs[b][(w * 2 + i) << 9];
        }
    }

    // prologue: DMA subtile 0 into buffer 0
#pragma unroll
    for (int i = 0; i < 2; ++i) {
        __builtin_amdgcn_global_load_lds((GV*)(void*)gk[i], (LV*)(void*)lk[0][i], 16, 0, 0);
        __builtin_amdgcn_global_load_lds((GV*)(void*)gv[i], (LV*)(void*)lv[0][i], 16, 0, 0);
    }

    for (int t = 0; t < 32; ++t) {
        const int buf = t & 1;
        __syncthreads();
        if (t < 31) {
#pragma unroll
            for (int i = 0; i < 2; ++i) {
                __builtin_amdgcn_global_load_lds((GV*)(void*)(gk[i] + (t + 1) * 4096), (LV*)(void*)lk[buf ^ 1][i], 16, 0, 0);
                __builtin_amdgcn_global_load_lds((GV*)(void*)(gv[i] + (t + 1) * 4096), (LV*)(void*)lv[buf ^ 1][i], 16, 0, 0);
            }
        }
        const unsigned short* KsB = Ks[buf];
        const unsigned short* VsB = Vs[buf];

        // ---- S^T = K * Q^T over 64 keys
        floatx4 sacc[2][4];
#pragma unroll
        for (int qt = 0; qt < 2; ++qt)
#pragma unroll
            for (int nt = 0; nt < 4; ++nt) sacc[qt][nt] = (floatx4){0.f, 0.f, 0.f, 0.f};
#pragma unroll
        for (int ks = 0; ks < 2; ++ks) {
#pragma unroll
            for (int nt = 0; nt < 4; ++nt) {
                short8 kf = *(const short8*)(KsB + (nt * 2 + ks) * 512 + lane * 8);
                sacc[0][nt] = __builtin_amdgcn_mfma_f32_16x16x32_bf16(kf, qf[0][ks], sacc[0][nt], 0, 0, 0);
                sacc[1][nt] = __builtin_amdgcn_mfma_f32_16x16x32_bf16(kf, qf[1][ks], sacc[1][nt], 0, 0, 0);
            }
        }

        // ---- softmax + PV over 32-key groups (native 16x16x32 f16)
#pragma unroll
        for (int u = 0; u < 2; ++u) {
            half8 pf[2];
#pragma unroll
            for (int qt = 0; qt < 2; ++qt) {
                floatx4 s0 = sacc[qt][2 * u];
                floatx4 s1 = sacc[qt][2 * u + 1];
                fp16x2 c0 = __builtin_amdgcn_cvt_pkrtz(ex2(s0[0]), ex2(s0[1]));
                fp16x2 c1 = __builtin_amdgcn_cvt_pkrtz(ex2(s0[2]), ex2(s0[3]));
                fp16x2 c2 = __builtin_amdgcn_cvt_pkrtz(ex2(s1[0]), ex2(s1[1]));
                fp16x2 c3 = __builtin_amdgcn_cvt_pkrtz(ex2(s1[2]), ex2(s1[3]));
                uint4v uu;
                uu.x = __builtin_bit_cast(unsigned int, c0);
                uu.y = __builtin_bit_cast(unsigned int, c1);
                uu.z = __builtin_bit_cast(unsigned int, c2);
                uu.w = __builtin_bit_cast(unsigned int, c3);
                pf[qt] = __builtin_bit_cast(half8, uu);
                lacc4[qt] = __builtin_amdgcn_mfma_f32_16x16x32_f16(pf[qt], vones, lacc4[qt], 0, 0, 0);
            }
#pragma unroll
            for (int nt = 0; nt < 4; ++nt) {
                uint4v vv = *(const uint4v*)(VsB + (u * 4 + nt) * 512 + lane * 8);
                half8 vf = __builtin_bit_cast(half8, vv);
                oacc[0][nt] = __builtin_amdgcn_mfma_f32_16x16x32_f16(pf[0], vf, oacc[0][nt], 0, 0, 0);
                oacc[1][nt] = __builtin_amdgcn_mfma_f32_16x16x32_f16(pf[1], vf, oacc[1][nt], 0, 0, 0);
            }
        }
    }

    // ---- epilogue: O /= l, write bf16
    const int b = bh >> 4, h = bh & 15;
#pragma unroll
    for (int qt = 0; qt < 2; ++qt) {
#pragma unroll
        for (int r = 0; r < 4; ++r) {
            float inv = 1.f / lacc4[qt][r];
            int n = q0 + w * 32 + qt * 16 + quad * 4 + r;
            size_t rowoff = ((size_t)b * SEQ + n) * NDIM + h * HD;
#pragma unroll
            for (int nt = 0; nt < 4; ++nt)
                ob[rowoff + nt * 16 + l15] = f2bf(oacc[qt][nt][r] * inv);
        }
    }
}

// ---------------------------------------------------------------- launch
extern "C" void kernel_launch(void* const* d_in, const int* in_sizes, int n_in,
                              void* d_out, int out_size, void* d_ws, size_t ws_size,
                              hipStream_t stream)
{
    (void)in_sizes; (void)n_in; (void)out_size; (void)ws_size;
    const float* x    = (const float*)d_in[0];
    const float* wqkv = (const float*)d_in[1];
    const float* wout = (const float*)d_in[2];
    const float* bout = (const float*)d_in[3];
    float* out = (float*)d_out;

    unsigned short* xb    = (unsigned short*)d_ws;
    unsigned short* wqkvb = xb    + 8388608;
    unsigned short* woutb = wqkvb + 3145728;
    unsigned short* qbuf  = woutb + 1048576;
    unsigned short* kbuf  = qbuf  + 8388608;
    unsigned short* vbuf  = kbuf  + 8388608;
    unsigned short* obuf  = vbuf  + 8388608;

    cast_f32_bf16<<<8192, 256, 0, stream>>>(x, xb);
    cast_f32_bf16<<<3072, 256, 0, stream>>>(wqkv, wqkvb);
    cast_f32_bf16<<<1024, 256, 0, stream>>>(wout, woutb);

    gemm_bt<0><<<dim3(64, 24), 256, 0, stream>>>(xb, wqkvb, qbuf, kbuf, vbuf, nullptr, nullptr);
    attn_fused<<<1024, 256, 0, stream>>>(qbuf, kbuf, vbuf, obuf);
    gemm_bt<1><<<dim3(64, 8), 256, 0, stream>>>(obuf, woutb, nullptr, nullptr, nullptr, bout, out);
}